// Round 1
// baseline (254.674 us; speedup 1.0000x reference)
//
#include <hip/hip_runtime.h>

#define K 7
#define KK 49
#define BLK 256

// Catmull-Rom cubic, a = -0.5
__device__ __forceinline__ float cubic_c(float x) {
    float ax  = __builtin_fabsf(x);
    float ax2 = ax * ax;
    float ax3 = ax2 * ax;
    float c01 =  1.5f * ax3 - 2.5f * ax2 + 1.0f;
    float c12 = -0.5f * ax3 + 2.5f * ax2 - 4.0f * ax + 2.0f;
    return (ax <= 1.0f) ? c01 : ((ax <= 2.0f) ? c12 : 0.0f);
}

__global__ __launch_bounds__(BLK) void kest_kernel(
    const float* __restrict__ m,
    const float* __restrict__ grid,
    const int*   __restrict__ Wp,
    const int*   __restrict__ yi,
    float*       __restrict__ out,
    int N)
{
    // sw[q][p]: weight q of pixel p (stride 257: (257*q+p)%32 = (q+p)%32,
    // at most 2-way bank aliasing on the transposed read = free)
    __shared__ float sw[KK][BLK + 1];
    __shared__ float srs[BLK];   // per-pixel 1/sum

    const int tid = threadIdx.x;
    const int i   = blockIdx.x * BLK + tid;

    const float m00 = m[0], m01 = m[1], m02 = m[2];
    const float m10 = m[3], m11 = m[4], m12 = m[5];
    const float m20 = m[6], m21 = m[7], m22 = m[8];
    const int   W   = Wp[0];

    if (i < N) {
        const int j = yi[i];
        const float xx = (float)(j % W);
        const float yy = (float)(j / W);

        // homography applied at pixel center
        const float X0 = m00 * xx + m01 * yy + m02;
        const float Y0 = m10 * xx + m11 * yy + m12;
        const float Z0 = m20 * xx + m21 * yy + m22;

        // du = pb - pt (eps_y = +/-0.5), stable difference-of-quotients:
        // (A+c)/(B+d) - (A-c)/(B-d) = 2(cB - dA)/(B^2 - d^2), c=0.5*m?1, d=0.5*m21
        const float izy = 1.0f / (Z0 * Z0 - 0.25f * m21 * m21);
        float du0 = (m01 * Z0 - m21 * X0) * izy;
        float du1 = (m11 * Z0 - m21 * Y0) * izy;
        // dv = pr - pl (eps_x = +/-0.5)
        const float izx = 1.0f / (Z0 * Z0 - 0.25f * m20 * m20);
        float dv0 = (m00 * Z0 - m20 * X0) * izx;
        float dv1 = (m10 * Z0 - m20 * Y0) * izx;

        // regularize |du| >= 1, |dv| >= 1
        float len_du = __builtin_sqrtf(du0 * du0 + du1 * du1);
        if (len_du < 1.0f) {
            float r = 1.0f / len_du;
            du0 *= r; du1 *= r;
            len_du = 1.0f;
        }
        float len_dv = __builtin_sqrtf(dv0 * dv0 + dv1 * dv1);
        if (len_dv < 1.0f) {
            float r = 1.0f / len_dv;
            dv0 *= r; dv1 *= r;
            len_dv = 1.0f;
        }

        const float det  = du0 * dv1 - du1 * dv0;
        const float r_du = 1.0f / (len_du * det);
        const float r_dv = 1.0f / (len_dv * det);

        // pos = grid + 1 - 0.5; frac part
        const float px = grid[i]     + 0.5f;
        const float py = grid[N + i] + 0.5f;
        const float fx = px - __builtin_floorf(px);
        const float fy = py - __builtin_floorf(py);

        float wsum = 0.0f;
#pragma unroll
        for (int ky = 0; ky < K; ++ky) {
            const float wyv = fy + 2.5f - (float)ky;
#pragma unroll
            for (int kx = 0; kx < K; ++kx) {
                const float wxv = fx + 2.5f - (float)kx;
                const float a = (dv1 * wxv - du1 * wyv) * r_du;
                const float b = (du0 * wyv - dv0 * wxv) * r_dv;
                const float x = du0 * a + du1 * b;
                const float y = dv0 * a + dv1 * b;
                const float wv = cubic_c(x) * cubic_c(y);
                sw[ky * K + kx][tid] = wv;
                wsum += wv;
            }
        }
        srs[tid] = 1.0f / wsum;
    }
    __syncthreads();

    // cooperative fully-coalesced store: element base+idx is pixel idx/49's
    // weight idx%49
    const long long base  = (long long)blockIdx.x * (BLK * KK);
    const long long limit = (long long)N * KK;
#pragma unroll
    for (int t = 0; t < KK; ++t) {
        const int idx = t * BLK + tid;
        const int p   = idx / KK;
        const int q   = idx - p * KK;
        const long long g = base + idx;
        if (g < limit) out[g] = sw[q][p] * srs[p];
    }
}

extern "C" void kernel_launch(void* const* d_in, const int* in_sizes, int n_in,
                              void* d_out, int out_size, void* d_ws, size_t ws_size,
                              hipStream_t stream) {
    // inputs: m_inverse(9 f32), grid(2N f32), H(1 i32), W(1 i32), yi(N i32)
    const float* m    = (const float*)d_in[0];
    const float* grid = (const float*)d_in[1];
    const int*   Wp   = (const int*)d_in[3];
    const int*   yi   = (const int*)d_in[4];
    float*       out  = (float*)d_out;
    const int N = in_sizes[4];

    const int blocks = (N + BLK - 1) / BLK;
    kest_kernel<<<blocks, BLK, 0, stream>>>(m, grid, Wp, yi, out, N);
}

// Round 2
// 217.668 us; speedup vs baseline: 1.1700x; 1.1700x over previous
//
#include <hip/hip_runtime.h>

#define K 7
#define KK 49
#define BLK 256
#define HALF_PIX 128                     // pixels staged per LDS chunk
#define CHUNK_FLOATS (HALF_PIX * KK)     // 6272 floats = 25088 B
#define CHUNK_F4 (CHUNK_FLOATS / 4)      // 1568 float4s

// Catmull-Rom a=-0.5, branchless truncated-power form:
// w = 0.5*t2^3 - 0.5*t2^2 + t1^2 - 2*t1^3,  t2=max(0,2-|x|), t1=max(0,1-|x|)
__device__ __forceinline__ float cubic_c(float x) {
    float ax = __builtin_fabsf(x);
    float t2 = __builtin_fmaxf(2.0f - ax, 0.0f);
    float t1 = __builtin_fmaxf(1.0f - ax, 0.0f);
    float r  = (t2 * t2) * __builtin_fmaf(0.5f, t2, -0.5f);
    return __builtin_fmaf(t1 * t1, __builtin_fmaf(-2.0f, t1, 1.0f), r);
}

__global__ __launch_bounds__(BLK, 5) void kest_kernel(
    const float* __restrict__ m,
    const float* __restrict__ grid,
    const int*   __restrict__ Wp,
    const int*   __restrict__ yi,
    float*       __restrict__ out,
    int N)
{
    __shared__ __align__(16) float lds[CHUNK_FLOATS];

    const int tid = threadIdx.x;
    const int i   = blockIdx.x * BLK + tid;
    const bool valid = (i < N);

    const float m00 = m[0], m01 = m[1], m02 = m[2];
    const float m10 = m[3], m11 = m[4], m12 = m[5];
    const float m20 = m[6], m21 = m[7], m22 = m[8];
    const int   W   = Wp[0];

    float w[KK];
    float rs = 0.0f;

    if (valid) {
        const int j = yi[i];
        const float xx = (float)(j % W);
        const float yy = (float)(j / W);

        const float X0 = m00 * xx + m01 * yy + m02;
        const float Y0 = m10 * xx + m11 * yy + m12;
        const float Z0 = m20 * xx + m21 * yy + m22;

        // stable difference-of-quotients for du (eps_y=±0.5) and dv (eps_x=±0.5)
        const float izy = 1.0f / (Z0 * Z0 - 0.25f * m21 * m21);
        float du0 = (m01 * Z0 - m21 * X0) * izy;
        float du1 = (m11 * Z0 - m21 * Y0) * izy;
        const float izx = 1.0f / (Z0 * Z0 - 0.25f * m20 * m20);
        float dv0 = (m00 * Z0 - m20 * X0) * izx;
        float dv1 = (m10 * Z0 - m20 * Y0) * izx;

        float len_du = __builtin_sqrtf(du0 * du0 + du1 * du1);
        if (len_du < 1.0f) {
            float r = 1.0f / len_du;
            du0 *= r; du1 *= r;
            len_du = 1.0f;
        }
        float len_dv = __builtin_sqrtf(dv0 * dv0 + dv1 * dv1);
        if (len_dv < 1.0f) {
            float r = 1.0f / len_dv;
            dv0 *= r; dv1 *= r;
            len_dv = 1.0f;
        }

        const float det  = du0 * dv1 - du1 * dv0;
        const float r_du = 1.0f / (len_du * det);
        const float r_dv = 1.0f / (len_dv * det);

        // x = Axx*wxv + Axy*wyv ; y = Ayx*wxv + Ayy*wyv
        const float Axx = du0 * dv1 * r_du - du1 * dv0 * r_dv;
        const float Axy = du0 * du1 * (r_dv - r_du);
        const float Ayx = dv0 * dv1 * (r_du - r_dv);
        const float Ayy = du0 * dv1 * r_dv - du1 * dv0 * r_du;

        const float px = grid[i]     + 0.5f;
        const float py = grid[N + i] + 0.5f;
        const float fx = px - __builtin_floorf(px);
        const float fy = py - __builtin_floorf(py);

        float wsum = 0.0f;
#pragma unroll
        for (int ky = 0; ky < K; ++ky) {
            const float wyv = fy + 2.5f - (float)ky;
            const float xk  = Axy * wyv;
            const float yk  = Ayy * wyv;
#pragma unroll
            for (int kx = 0; kx < K; ++kx) {
                const float wxv = fx + 2.5f - (float)kx;
                const float x = __builtin_fmaf(Axx, wxv, xk);
                const float y = __builtin_fmaf(Ayx, wxv, yk);
                const float wv = cubic_c(x) * cubic_c(y);
                w[ky * K + kx] = wv;
                wsum += wv;
            }
        }
        rs = 1.0f / wsum;
    }

    const long long blockBaseF = (long long)blockIdx.x * (BLK * KK); // in floats
    const long long limitF4    = ((long long)N * KK) >> 2;           // float4 bound

    // ---- phase A: pixels [0,128) of this block ----
    if (valid && tid < HALF_PIX) {
        float* p = &lds[tid * KK];
#pragma unroll
        for (int q = 0; q < KK; ++q) p[q] = w[q] * rs;
    }
    __syncthreads();
    {
        const float4* src = (const float4*)lds;
        float4*       dst = (float4*)(out + blockBaseF);
        const long long g0 = blockBaseF >> 2;
#pragma unroll
        for (int t = tid; t < CHUNK_F4; t += BLK) {
            if (g0 + t < limitF4) dst[t] = src[t];
        }
    }
    __syncthreads();

    // ---- phase B: pixels [128,256) ----
    if (valid && tid >= HALF_PIX) {
        float* p = &lds[(tid - HALF_PIX) * KK];
#pragma unroll
        for (int q = 0; q < KK; ++q) p[q] = w[q] * rs;
    }
    __syncthreads();
    {
        const float4* src = (const float4*)lds;
        float4*       dst = (float4*)(out + blockBaseF + CHUNK_FLOATS);
        const long long g0 = (blockBaseF + CHUNK_FLOATS) >> 2;
#pragma unroll
        for (int t = tid; t < CHUNK_F4; t += BLK) {
            if (g0 + t < limitF4) dst[t] = src[t];
        }
    }
}

extern "C" void kernel_launch(void* const* d_in, const int* in_sizes, int n_in,
                              void* d_out, int out_size, void* d_ws, size_t ws_size,
                              hipStream_t stream) {
    // inputs: m_inverse(9 f32), grid(2N f32), H(1 i32), W(1 i32), yi(N i32)
    const float* m    = (const float*)d_in[0];
    const float* grid = (const float*)d_in[1];
    const int*   Wp   = (const int*)d_in[3];
    const int*   yi   = (const int*)d_in[4];
    float*       out  = (float*)d_out;
    const int N = in_sizes[4];

    const int blocks = (N + BLK - 1) / BLK;
    kest_kernel<<<blocks, BLK, 0, stream>>>(m, grid, Wp, yi, out, N);
}